// Round 17
// baseline (769.549 us; speedup 1.0000x reference)
//
#include <hip/hip_runtime.h>
#include <stdint.h>

// ---------------- problem dims ----------------
static constexpr int B      = 16;
static constexpr int N      = 128;
static constexpr int P      = 4064;     // 32*(128-1)
static constexpr int MPOSE  = 64;
static constexpr int64_t BN = (int64_t)B * N;   // 2048
static constexpr int64_t BP = (int64_t)B * P;   // 65024 = 508*128

#define TWO_PI 6.283185307179586f
#define QSCALE 0.17677669529663687f  /* 1/sqrt(32) */

typedef __attribute__((ext_vector_type(4))) float f32x4;
typedef __attribute__((ext_vector_type(8))) short bf16x8;
typedef __attribute__((ext_vector_type(8))) unsigned short u16x8;
typedef __attribute__((ext_vector_type(4))) unsigned short u16x4;

__device__ __forceinline__ unsigned short f2bf(float f) {
    union { float f; unsigned u; } v; v.f = f;
    unsigned r = (v.u + 0x7fffu + ((v.u >> 16) & 1u)) >> 16;   // RNE
    return (unsigned short)r;
}
__device__ __forceinline__ float bf2f(unsigned short u) {
    union { unsigned u; float f; } v; v.u = (unsigned)u << 16;
    return v.f;
}
__device__ __forceinline__ void pair_xy(int p, int& x, int& y) {
    x = p / 127;
    int r = p - x * 127;
    y = (r < x) ? r : r + 1;
}
// bijective XCD-chunked swizzle (m204)
__device__ __forceinline__ int xcd_swz(int orig, int nwg) {
    int q = nwg >> 3, r = nwg & 7;
    int xcd = orig & 7, idx = orig >> 3;
    return (xcd < r ? xcd * (q + 1) : r * (q + 1) + (xcd - r) * q) + idx;
}
// async global->LDS, 16B per lane
__device__ __forceinline__ void gld16(const unsigned short* g, unsigned short* l) {
    __builtin_amdgcn_global_load_lds(
        (const __attribute__((address_space(1))) void*)g,
        (__attribute__((address_space(3))) void*)l, 16, 0, 0);
}

// ---------------- batched weight prep: W[K][N] fp32 -> Wt[N][Kpad] bf16 ----------------
struct WDesc { const float* src; int64_t dstOff; int K, Nn, Kpad, blockStart; };
struct WTable { WDesc d[29]; int nDesc; };

__global__ __launch_bounds__(256) void wprep_all_k(WTable t, unsigned short* __restrict__ wt)
{
    __shared__ float s[32][33];
    int bid = blockIdx.x;
    int di = 0;
    for (int i = 1; i < t.nDesc; ++i) if (t.d[i].blockStart <= bid) di = i;
    const WDesc& d = t.d[di];
    int lbid = bid - d.blockStart;
    int kTiles = d.Kpad >> 5;
    int k0 = (lbid % kTiles) * 32, n0 = (lbid / kTiles) * 32;
    int tx = threadIdx.x & 31, ty = threadIdx.x >> 5;
#pragma unroll
    for (int i = 0; i < 4; ++i) {
        int k = k0 + ty + i * 8;
        s[ty + i * 8][tx] = (k < d.K) ? d.src[(int64_t)k * d.Nn + n0 + tx] : 0.f;
    }
    __syncthreads();
    unsigned short* dst = wt + d.dstOff;
#pragma unroll
    for (int i = 0; i < 4; ++i) {
        int n = n0 + ty + i * 8;
        dst[(int64_t)n * d.Kpad + k0 + tx] = f2bf(s[tx][ty + i * 8]);
    }
}

// ---------------- fp32-A bf16 MFMA GEMM (token stages), 128x128 tile ----------------
template <bool RELU_OUT>
__global__ __launch_bounds__(256) void bgemm_k(
    const float* __restrict__ A, const float* __restrict__ A2, int lda,
    const unsigned short* __restrict__ Bt, int ldk,
    const float* __restrict__ bias,
    const float* __restrict__ Cadd, int addStride, int addCols,
    const float* __restrict__ lfp,
    float* __restrict__ C, int ldc,
    int kSteps)
{
    __shared__ unsigned short As[128][40];
    __shared__ unsigned short Bs[128][40];
    const int tid  = threadIdx.x;
    const int lane = tid & 63;
    const int wave = tid >> 6;
    const int wr = wave >> 1, wc = wave & 1;
    const int row0 = blockIdx.y * 128, col0 = blockIdx.x * 128;
    const int l15 = lane & 15, l4 = lane >> 4;
    const int sr = tid >> 1;
    const int sh = (tid & 1) * 16;

    f32x4 acc[4][4] = {};

    for (int ks = 0; ks < kSteps; ++ks) {
        const int k0 = ks * 32;
        {
            const int64_t off = (int64_t)(row0 + sr) * lda + k0 + sh;
            const float* ap = A + off;
            float v[16];
#pragma unroll
            for (int i = 0; i < 4; ++i) {
                float4 tv = ((const float4*)ap)[i];
                v[i*4+0] = tv.x; v[i*4+1] = tv.y; v[i*4+2] = tv.z; v[i*4+3] = tv.w;
            }
            if (A2) {
                const float* ap2 = A2 + off;
#pragma unroll
                for (int i = 0; i < 4; ++i) {
                    float4 tv = ((const float4*)ap2)[i];
                    v[i*4+0] += tv.x; v[i*4+1] += tv.y; v[i*4+2] += tv.z; v[i*4+3] += tv.w;
                }
            }
            u16x8 p0, p1;
#pragma unroll
            for (int j = 0; j < 8; ++j) { p0[j] = f2bf(v[j]); p1[j] = f2bf(v[8 + j]); }
            *(u16x8*)&As[sr][sh]     = p0;
            *(u16x8*)&As[sr][sh + 8] = p1;
        }
        {
            const unsigned short* bp = Bt + (int64_t)(col0 + sr) * ldk + k0 + sh;
            *(u16x8*)&Bs[sr][sh]     = *(const u16x8*)bp;
            *(u16x8*)&Bs[sr][sh + 8] = *(const u16x8*)(bp + 8);
        }
        __syncthreads();
        bf16x8 af[4], bfr[4];
#pragma unroll
        for (int f = 0; f < 4; ++f) {
            af[f]  = *(const bf16x8*)&As[wr * 64 + f * 16 + l15][l4 * 8];
            bfr[f] = *(const bf16x8*)&Bs[wc * 64 + f * 16 + l15][l4 * 8];
        }
#pragma unroll
        for (int i = 0; i < 4; ++i)
#pragma unroll
            for (int j = 0; j < 4; ++j)
                acc[i][j] = __builtin_amdgcn_mfma_f32_16x16x32_bf16(af[i], bfr[j], acc[i][j], 0, 0, 0);
        __syncthreads();
    }
#pragma unroll
    for (int i = 0; i < 4; ++i) {
        int rb = row0 + wr * 64 + i * 16 + l4 * 4;
#pragma unroll
        for (int j = 0; j < 4; ++j) {
            int c = col0 + wc * 64 + j * 16 + l15;
            float bv = bias ? bias[c] : 0.f;
#pragma unroll
            for (int e = 0; e < 4; ++e) {
                int r = rb + e;
                float vv = acc[i][j][e] + bv;
                if (Cadd && c < addCols) vv += Cadd[(int64_t)r * addStride + c];
                if (lfp) vv += lfp[(r >> 7) * 256 + c];
                if (RELU_OUT) vv = fmaxf(vv, 0.f);
                C[(int64_t)r * ldc + c] = vv;
            }
        }
    }
}

static void bgemm(hipStream_t st,
                  const float* A, const float* A2, int lda,
                  const unsigned short* Bt, int ldk, const float* bias,
                  const float* Cadd, int addStride, int addCols, const float* lfp,
                  float* C, int ldc, int M, int Ncols, int K, bool reluOut)
{
    dim3 g(Ncols / 128, M / 128), b(256);
    if (reluOut) bgemm_k<true><<<g,b,0,st>>>(A,A2,lda,Bt,ldk,bias,Cadd,addStride,addCols,lfp,C,ldc,K/32);
    else         bgemm_k<false><<<g,b,0,st>>>(A,A2,lda,Bt,ldk,bias,Cadd,addStride,addCols,lfp,C,ldc,K/32);
}

// ---------------- token GEMM 16x256 + residual + LayerNorm epilogue (128 blocks) ----------------
__global__ __launch_bounds__(256) void tgemm16_k(
    const float* __restrict__ A, int lda,
    const unsigned short* __restrict__ Bt, int ldk,
    const float* __restrict__ bias,
    const float* __restrict__ res,
    const float* __restrict__ g, const float* __restrict__ be,
    float* __restrict__ C, int kSteps)
{
    __shared__ unsigned short As[16][40];
    __shared__ unsigned short Bs[256][40];
    __shared__ float partS[16][4], partQ[16][4];
    __shared__ float statM[16], statI[16];
    const int tid = threadIdx.x;
    const int lane = tid & 63, w = tid >> 6;
    const int l15 = lane & 15, l4 = lane >> 4;
    const int row0 = blockIdx.x * 16;

    f32x4 acc[4] = {};
    for (int ks = 0; ks < kSteps; ++ks) {
        int k0 = ks * 32;
        if (tid < 64) {
            const float* ap = A + (int64_t)(row0 + (tid >> 2)) * lda + k0 + (tid & 3) * 8;
            float4 t0 = ((const float4*)ap)[0];
            float4 t1 = ((const float4*)ap)[1];
            u16x8 p;
            p[0]=f2bf(t0.x); p[1]=f2bf(t0.y); p[2]=f2bf(t0.z); p[3]=f2bf(t0.w);
            p[4]=f2bf(t1.x); p[5]=f2bf(t1.y); p[6]=f2bf(t1.z); p[7]=f2bf(t1.w);
            *(u16x8*)&As[tid >> 2][(tid & 3) * 8] = p;
        }
        {
            const unsigned short* bp = Bt + (int64_t)tid * ldk + k0;
#pragma unroll
            for (int q = 0; q < 4; ++q)
                *(u16x8*)&Bs[tid][q * 8] = *(const u16x8*)(bp + q * 8);
        }
        __syncthreads();
        bf16x8 af = *(const bf16x8*)&As[l15][l4 * 8];
        bf16x8 bfr[4];
#pragma unroll
        for (int f = 0; f < 4; ++f)
            bfr[f] = *(const bf16x8*)&Bs[w * 64 + f * 16 + l15][l4 * 8];
#pragma unroll
        for (int j = 0; j < 4; ++j)
            acc[j] = __builtin_amdgcn_mfma_f32_16x16x32_bf16(af, bfr[j], acc[j], 0, 0, 0);
        __syncthreads();
    }
    float ps[4] = {}, pq[4] = {};
#pragma unroll
    for (int j = 0; j < 4; ++j) {
        int c = w * 64 + j * 16 + l15;
#pragma unroll
        for (int e = 0; e < 4; ++e) {
            int r = l4 * 4 + e;
            float v = acc[j][e] + bias[c] + res[(int64_t)(row0 + r) * 256 + c];
            acc[j][e] = v;
            ps[e] += v;
            pq[e] += v * v;
        }
    }
#pragma unroll
    for (int e = 0; e < 4; ++e) {
#pragma unroll
        for (int m = 1; m < 16; m <<= 1) {
            ps[e] += __shfl_xor(ps[e], m);
            pq[e] += __shfl_xor(pq[e], m);
        }
    }
    if (l15 == 0) {
#pragma unroll
        for (int e = 0; e < 4; ++e) {
            int r = l4 * 4 + e;
            partS[r][w] = ps[e];
            partQ[r][w] = pq[e];
        }
    }
    __syncthreads();
    if (tid < 16) {
        float s = partS[tid][0] + partS[tid][1] + partS[tid][2] + partS[tid][3];
        float q = partQ[tid][0] + partQ[tid][1] + partQ[tid][2] + partQ[tid][3];
        float m = s * (1.f/256.f);
        float var = q * (1.f/256.f) - m * m;
        statM[tid] = m;
        statI[tid] = rsqrtf(var + 1e-5f);
    }
    __syncthreads();
#pragma unroll
    for (int j = 0; j < 4; ++j) {
        int c = w * 64 + j * 16 + l15;
#pragma unroll
        for (int e = 0; e < 4; ++e) {
            int r = l4 * 4 + e;
            C[(int64_t)(row0 + r) * 256 + c] = (acc[j][e] - statM[r]) * statI[r] * g[c] + be[c];
        }
    }
}

// ---------------- bf16 MFMA GEMM (pair stages): 3-deep pipeline, counted vmcnt, NT col-tiles ----------------
// Block computes 128 rows x (NT*128) cols; A staged once per K-step regardless of NT.
template <int NT, bool RELU_OUT, bool OUT_BF16>
__global__ __launch_bounds__(256) void hgemm_k(
    const unsigned short* __restrict__ A, int lda,
    const unsigned short* __restrict__ Bt, int ldk,
    const float* __restrict__ bias,
    void* __restrict__ Cv, int ldc,
    int kSteps, int nx)
{
    __shared__ unsigned short As[3][128][32];
    __shared__ unsigned short Bs[3][NT * 128][32];
    const int tid  = threadIdx.x;
    const int lane = tid & 63;
    const int wave = tid >> 6;
    const int wr = wave >> 1, wc = wave & 1;
    const int wgid = xcd_swz(blockIdx.x, gridDim.x);
    const int row0 = (wgid / nx) * 128, col0 = (wgid % nx) * 128 * NT;
    const int l15 = lane & 15, l4 = lane >> 4;
    const int srow = lane >> 2;
    const int scol = (lane & 3) * 8;

    f32x4 acc[4][4 * NT] = {};

    // prologue: stage T0 -> buf0, T1 -> buf1
#pragma unroll
    for (int t = 0; t < 2; ++t) {
        const int k0 = t * 32;
#pragma unroll
        for (int i = 0; i < 2; ++i) {
            int seg = wave * 2 + i;
            int r = seg * 16 + srow;
            gld16(A + (int64_t)(row0 + r) * lda + k0 + scol, &As[t][seg * 16][0]);
        }
#pragma unroll
        for (int i = 0; i < 2 * NT; ++i) {
            int seg = wave * 2 * NT + i;
            int r = seg * 16 + srow;
            gld16(Bt + (int64_t)(col0 + r) * ldk + k0 + scol, &Bs[t][seg * 16][0]);
        }
    }

    int cur = 0;
    for (int ks = 0; ks < kSteps; ++ks) {
        // wait for oldest in-flight tile only (counted); per-tile loads/wave = 2 + 2*NT
        if (ks + 1 < kSteps) {
            if constexpr (NT == 1) asm volatile("s_waitcnt vmcnt(4)" ::: "memory");
            else                   asm volatile("s_waitcnt vmcnt(6)" ::: "memory");
        } else {
            asm volatile("s_waitcnt vmcnt(0)" ::: "memory");
        }
        __builtin_amdgcn_s_barrier();
        asm volatile("" ::: "memory");
        // issue T(ks+2) into buf (cur+2)%3
        if (ks + 2 < kSteps) {
            const int nb = (cur + 2 >= 3) ? cur - 1 : cur + 2;
            const int k0n = (ks + 2) * 32;
#pragma unroll
            for (int i = 0; i < 2; ++i) {
                int seg = wave * 2 + i;
                int r = seg * 16 + srow;
                gld16(A + (int64_t)(row0 + r) * lda + k0n + scol, &As[nb][seg * 16][0]);
            }
#pragma unroll
            for (int i = 0; i < 2 * NT; ++i) {
                int seg = wave * 2 * NT + i;
                int r = seg * 16 + srow;
                gld16(Bt + (int64_t)(col0 + r) * ldk + k0n + scol, &Bs[nb][seg * 16][0]);
            }
        }
        // compute current tile
        bf16x8 af[4], bfr[NT][4];
#pragma unroll
        for (int f = 0; f < 4; ++f)
            af[f] = *(const bf16x8*)&As[cur][wr * 64 + f * 16 + l15][l4 * 8];
#pragma unroll
        for (int ct = 0; ct < NT; ++ct)
#pragma unroll
            for (int f = 0; f < 4; ++f)
                bfr[ct][f] = *(const bf16x8*)&Bs[cur][ct * 128 + wc * 64 + f * 16 + l15][l4 * 8];
#pragma unroll
        for (int i = 0; i < 4; ++i)
#pragma unroll
            for (int ct = 0; ct < NT; ++ct)
#pragma unroll
                for (int j = 0; j < 4; ++j)
                    acc[i][ct * 4 + j] = __builtin_amdgcn_mfma_f32_16x16x32_bf16(
                        af[i], bfr[ct][j], acc[i][ct * 4 + j], 0, 0, 0);
        __builtin_amdgcn_s_barrier();   // all waves done reading buf cur before re-stage
        cur = (cur + 1 >= 3) ? 0 : cur + 1;
    }
#pragma unroll
    for (int i = 0; i < 4; ++i) {
        int rb = row0 + wr * 64 + i * 16 + l4 * 4;
#pragma unroll
        for (int ct = 0; ct < NT; ++ct)
#pragma unroll
        for (int j = 0; j < 4; ++j) {
            int c = col0 + ct * 128 + wc * 64 + j * 16 + l15;
            float bv = bias ? bias[c] : 0.f;
#pragma unroll
            for (int e = 0; e < 4; ++e) {
                int64_t off = (int64_t)(rb + e) * ldc + c;
                float vv = acc[i][ct * 4 + j][e] + bv;
                if (RELU_OUT) vv = fmaxf(vv, 0.f);
                if (OUT_BF16) ((unsigned short*)Cv)[off] = f2bf(vv);
                else          ((float*)Cv)[off] = vv;
            }
        }
    }
}

// ---------------- spa_k: f36 (in-kernel) -> sw1 -> sw2 -> t3 bf16 ----------------
__global__ __launch_bounds__(256) void spa_k(
    const float* __restrict__ boxes, const float* __restrict__ sizes,
    const unsigned short* __restrict__ W1, const float* __restrict__ b1,
    const unsigned short* __restrict__ W2, const float* __restrict__ b2,
    unsigned short* __restrict__ t3out, int chunk0)
{
    __shared__ unsigned short F[128][72];
    __shared__ unsigned short Bs[128][40];
    __shared__ unsigned short D1s[128][136];
    const int tid  = threadIdx.x;
    const int lane = tid & 63;
    const int wave = tid >> 6;
    const int wr = wave >> 1, wc = wave & 1;
    const int row0 = blockIdx.x * 128;
    const int l15 = lane & 15, l4 = lane >> 4;
    const int sr = tid >> 1;
    const int sh = (tid & 1) * 16;

    if (tid < 128) {
        int gp = chunk0 + row0 + tid;
        int b = gp / P, p = gp - b * P;
        int xi, yi; pair_xy(p, xi, yi);
        const float* b1x = boxes + ((int64_t)b * N + xi) * 4;
        const float* b2x = boxes + ((int64_t)b * N + yi) * 4;
        float h = sizes[b * 2 + 0], w = sizes[b * 2 + 1];
        float c1x = (b1x[0] + b1x[2]) * 0.5f, c1y = (b1x[1] + b1x[3]) * 0.5f;
        float c2x = (b2x[0] + b2x[2]) * 0.5f, c2y = (b2x[1] + b2x[3]) * 0.5f;
        float w1 = b1x[2] - b1x[0], h1 = b1x[3] - b1x[1];
        float w2 = b2x[2] - b2x[0], h2 = b2x[3] - b2x[1];
        float a1 = w1 * h1, a2 = w2 * h2;
        float dx = fabsf(c2x - c1x) / (w1 + 1e-6f);
        float dy = fabsf(c2y - c1y) / (h1 + 1e-6f);
        float ix = fmaxf(fminf(b1x[2], b2x[2]) - fmaxf(b1x[0], b2x[0]), 0.f);
        float iy = fmaxf(fminf(b1x[3], b2x[3]) - fmaxf(b1x[1], b2x[1]), 0.f);
        float inter = ix * iy;
        float iou = inter / (a1 + a2 - inter + 1e-6f);
        float f[18];
        f[0] = c1x / w;  f[1] = c1y / h;  f[2] = c2x / w;  f[3] = c2y / h;
        f[4] = w1 / w;   f[5] = h1 / h;   f[6] = w2 / w;   f[7] = h2 / h;
        f[8] = a1 / (h * w); f[9] = a2 / (h * w); f[10] = a2 / (a1 + 1e-6f);
        f[11] = w1 / (h1 + 1e-6f); f[12] = w2 / (h2 + 1e-6f); f[13] = iou;
        f[14] = (c2x > c1x) ? dx : 0.f;  f[15] = (c2x < c1x) ? dx : 0.f;
        f[16] = (c2y > c1y) ? dy : 0.f;  f[17] = (c2y < c1y) ? dy : 0.f;
#pragma unroll
        for (int i = 0; i < 18; ++i) {
            F[tid][i]      = f2bf(f[i]);
            F[tid][18 + i] = f2bf(logf(f[i] + 1e-6f));
        }
#pragma unroll
        for (int i = 36; i < 64; ++i) F[tid][i] = 0;
    }
    __syncthreads();

    f32x4 acc1[4][4] = {};
    for (int ks = 0; ks < 2; ++ks) {
        const int k0 = ks * 32;
        {
            const unsigned short* bp = W1 + (int64_t)sr * 64 + k0 + sh;
            *(u16x8*)&Bs[sr][sh]     = *(const u16x8*)bp;
            *(u16x8*)&Bs[sr][sh + 8] = *(const u16x8*)(bp + 8);
        }
        __syncthreads();
        bf16x8 af[4], bfr[4];
#pragma unroll
        for (int f = 0; f < 4; ++f) {
            af[f]  = *(const bf16x8*)&F[wr * 64 + f * 16 + l15][k0 + l4 * 8];
            bfr[f] = *(const bf16x8*)&Bs[wc * 64 + f * 16 + l15][l4 * 8];
        }
#pragma unroll
        for (int i = 0; i < 4; ++i)
#pragma unroll
            for (int j = 0; j < 4; ++j)
                acc1[i][j] = __builtin_amdgcn_mfma_f32_16x16x32_bf16(af[i], bfr[j], acc1[i][j], 0, 0, 0);
        __syncthreads();
    }
#pragma unroll
    for (int i = 0; i < 4; ++i) {
        int rb = wr * 64 + i * 16 + l4 * 4;
#pragma unroll
        for (int j = 0; j < 4; ++j) {
            int c = wc * 64 + j * 16 + l15;
            float bv = b1[c];
#pragma unroll
            for (int e = 0; e < 4; ++e)
                D1s[rb + e][c] = f2bf(fmaxf(acc1[i][j][e] + bv, 0.f));
        }
    }
    __syncthreads();

    f32x4 acc2[2][4][4] = {};
#pragma unroll
    for (int n = 0; n < 2; ++n) {
        for (int kk = 0; kk < 4; ++kk) {
            {
                const unsigned short* bp = W2 + (int64_t)(n * 128 + sr) * 128 + kk * 32 + sh;
                *(u16x8*)&Bs[sr][sh]     = *(const u16x8*)bp;
                *(u16x8*)&Bs[sr][sh + 8] = *(const u16x8*)(bp + 8);
            }
            __syncthreads();
            bf16x8 af[4], bfr[4];
#pragma unroll
            for (int f = 0; f < 4; ++f) {
                af[f]  = *(const bf16x8*)&D1s[wr * 64 + f * 16 + l15][kk * 32 + l4 * 8];
                bfr[f] = *(const bf16x8*)&Bs[wc * 64 + f * 16 + l15][l4 * 8];
            }
#pragma unroll
            for (int i = 0; i < 4; ++i)
#pragma unroll
                for (int j = 0; j < 4; ++j)
                    acc2[n][i][j] = __builtin_amdgcn_mfma_f32_16x16x32_bf16(af[i], bfr[j], acc2[n][i][j], 0, 0, 0);
            __syncthreads();
        }
    }
#pragma unroll
    for (int n = 0; n < 2; ++n)
#pragma unroll
    for (int i = 0; i < 4; ++i) {
        int rb = row0 + wr * 64 + i * 16 + l4 * 4;
#pragma unroll
        for (int j = 0; j < 4; ++j) {
            int c = n * 128 + wc * 64 + j * 16 + l15;
            float bv = b2[c];
#pragma unroll
            for (int e = 0; e < 4; ++e)
                t3out[(int64_t)(rb + e) * 256 + c] = f2bf(fmaxf(acc2[n][i][j][e] + bv, 0.f));
        }
    }
}

// ---------------- zprep_k: zb = [relu(LN(U+V+fc1_b)) | relu(LN(t3))] bf16 ----------------
__global__ __launch_bounds__(256) void zprep_k(
    const float* __restrict__ UV, const float* __restrict__ fb,
    const unsigned short* __restrict__ t3,
    const float* __restrict__ g1, const float* __restrict__ be1,
    const float* __restrict__ g2, const float* __restrict__ be2,
    unsigned short* __restrict__ zb, int chunk0, int rows)
{
    int wave = threadIdx.x >> 6, lane = threadIdx.x & 63;
    int li = blockIdx.x * 4 + wave;
    if (li >= rows) return;
    int gp = chunk0 + li;
    int b = gp / P, p = gp - b * P;
    int xi, yi; pair_xy(p, xi, yi);
    int c = lane * 4;
    {
        float4 u  = *(const float4*)(UV + ((int64_t)(b * 128 + xi)) * 512 + c);
        float4 vv = *(const float4*)(UV + ((int64_t)(b * 128 + yi)) * 512 + 256 + c);
        float4 fbv = *(const float4*)(fb + c);
        float4 v;
        v.x = u.x + vv.x + fbv.x; v.y = u.y + vv.y + fbv.y;
        v.z = u.z + vv.z + fbv.z; v.w = u.w + vv.w + fbv.w;
        float s  = v.x + v.y + v.z + v.w;
        float sq = v.x*v.x + v.y*v.y + v.z*v.z + v.w*v.w;
#pragma unroll
        for (int off = 1; off < 64; off <<= 1) {
            s  += __shfl_xor(s, off);
            sq += __shfl_xor(sq, off);
        }
        float m = s * (1.f/256.f);
        float var = sq * (1.f/256.f) - m * m;
        float inv = rsqrtf(var + 1e-5f);
        float4 gg = *(const float4*)(g1 + c);
        float4 bb = *(const float4*)(be1 + c);
        u16x4 o;
        o[0] = f2bf(fmaxf((v.x - m) * inv * gg.x + bb.x, 0.f));
        o[1] = f2bf(fmaxf((v.y - m) * inv * gg.y + bb.y, 0.f));
        o[2] = f2bf(fmaxf((v.z - m) * inv * gg.z + bb.z, 0.f));
        o[3] = f2bf(fmaxf((v.w - m) * inv * gg.w + bb.w, 0.f));
        *(u16x4*)(zb + (int64_t)li * 512 + c) = o;
    }
    {
        u16x4 u = *(const u16x4*)(t3 + (int64_t)li * 256 + c);
        float4 v;
        v.x = bf2f(u[0]); v.y = bf2f(u[1]); v.z = bf2f(u[2]); v.w = bf2f(u[3]);
        float s  = v.x + v.y + v.z + v.w;
        float sq = v.x*v.x + v.y*v.y + v.z*v.z + v.w*v.w;
#pragma unroll
        for (int off = 1; off < 64; off <<= 1) {
            s  += __shfl_xor(s, off);
            sq += __shfl_xor(sq, off);
        }
        float m = s * (1.f/256.f);
        float var = sq * (1.f/256.f) - m * m;
        float inv = rsqrtf(var + 1e-5f);
        float4 gg = *(const float4*)(g2 + c);
        float4 bb = *(const float4*)(be2 + c);
        u16x4 o;
        o[0] = f2bf(fmaxf((v.x - m) * inv * gg.x + bb.x, 0.f));
        o[1] = f2bf(fmaxf((v.y - m) * inv * gg.y + bb.y, 0.f));
        o[2] = f2bf(fmaxf((v.z - m) * inv * gg.z + bb.z, 0.f));
        o[3] = f2bf(fmaxf((v.w - m) * inv * gg.w + bb.w, 0.f));
        *(u16x4*)(zb + (int64_t)li * 512 + 256 + c) = o;
    }
}

// ---------------- line: mean over 8x8, then proj ----------------
__global__ __launch_bounds__(256) void line_mean_k(const float* __restrict__ line, float* __restrict__ lm)
{
    int wave = threadIdx.x >> 6, lane = threadIdx.x & 63;
    int bc = blockIdx.x * 4 + wave;
    float v = line[(int64_t)bc * 64 + lane];
#pragma unroll
    for (int off = 1; off < 64; off <<= 1) v += __shfl_xor(v, off);
    if (lane == 0) lm[bc] = v * (1.f/64.f);
}

__global__ __launch_bounds__(256) void line_proj_k(
    const float* __restrict__ lm, const float* __restrict__ lw,
    const float* __restrict__ lb, float* __restrict__ lf)
{
    __shared__ float red[8][32];
    int b = blockIdx.y, jg = blockIdx.x;
    int jj = threadIdx.x & 31, cc = threadIdx.x >> 5;
    int j = jg * 32 + jj;
    const float* lmb = lm + (int64_t)b * 2048 + cc * 256;
    const float* lwp = lw + (int64_t)(cc * 256) * 256 + j;
    float acc = 0.f;
#pragma unroll 4
    for (int k = 0; k < 256; ++k) acc += lmb[k] * lwp[(int64_t)k * 256];
    red[cc][jj] = acc;
    __syncthreads();
    if (cc == 0) {
        float s = lb[j];
#pragma unroll
        for (int i = 0; i < 8; ++i) s += red[i][jj];
        lf[b * 256 + j] = s;
    }
}

// ---------------- sinusoidal box PE ----------------
__global__ __launch_bounds__(512) void boxpe_k(
    const float* __restrict__ boxes, const float* __restrict__ sizes, float* __restrict__ boxpe)
{
    int row = blockIdx.x;
    int b = row >> 7;
    int i = threadIdx.x;
    const float* bx = boxes + (int64_t)row * 4;
    float h = sizes[b * 2 + 0], w = sizes[b * 2 + 1];
    float x0 = bx[0] / w, y0 = bx[1] / h, x1 = bx[2] / w, y1 = bx[3] / h;
    int seg = i >> 7, j = i & 127, k = j >> 1;
    float val;
    switch (seg) {
        case 0: val = (y0 + y1) * 0.5f; break;
        case 1: val = (x0 + x1) * 0.5f; break;
        case 2: val = (y1 - y0); break;
        default: val = (x1 - x0); break;
    }
    float dimt = exp2f((float)k * (4.321928094887362f / 64.f));
    float arg = val * TWO_PI / dimt;
    boxpe[(int64_t)row * 512 + i] = (j & 1) ? cosf(arg) : sinf(arg);
}

// ---------------- encoder self-attn (4 lanes/query): qkv = [2048][768] ----------------
__global__ __launch_bounds__(256) void enc_attn_k(
    const float* __restrict__ qkv, float* __restrict__ outp)
{
    int bh = blockIdx.x >> 1;
    int qt = blockIdx.x & 1;
    int b = bh >> 3, hd = bh & 7;
    __shared__ float kl[128][32];
    __shared__ float vl[128][32];
    int tid = threadIdx.x;
    for (int i = tid; i < 128 * 32; i += 256) {
        int s = i >> 5, j = i & 31;
        const float* rp = qkv + ((int64_t)(b * 128 + s)) * 768 + hd * 32 + j;
        kl[s][j] = rp[256];
        vl[s][j] = rp[512];
    }
    __syncthreads();
    int q  = qt * 64 + (tid >> 2);
    int qu = (tid & 3) * 8;
    const float* qp = qkv + ((int64_t)(b * 128 + q)) * 768 + hd * 32 + qu;
    float qr[8];
#pragma unroll
    for (int j = 0; j < 8; ++j) qr[j] = qp[j] * QSCALE;
    float m = -1e30f, l = 0.f;
    for (int s = 0; s < 128; ++s) {
        float d = 0.f;
#pragma unroll
        for (int j = 0; j < 8; ++j) d += qr[j] * kl[s][qu + j];
        d += __shfl_xor(d, 1);
        d += __shfl_xor(d, 2);
        float mn = fmaxf(m, d);
        l = l * __expf(m - mn) + __expf(d - mn);
        m = mn;
    }
    float acc[8] = {};
    for (int s = 0; s < 128; ++s) {
        float d = 0.f;
#pragma unroll
        for (int j = 0; j < 8; ++j) d += qr[j] * kl[s][qu + j];
        d += __shfl_xor(d, 1);
        d += __shfl_xor(d, 2);
        float wgt = __expf(d - m);
#pragma unroll
        for (int j = 0; j < 8; ++j) acc[j] += wgt * vl[s][qu + j];
    }
    float linv = 1.f / l;
    float* op = outp + ((int64_t)(b * 128 + q)) * 256 + hd * 32 + qu;
#pragma unroll
    for (int j = 0; j < 8; ++j) op[j] = acc[j] * linv;
}

// ---------------- decoder cross-attn (4 lanes/query): kv stride ldkv, k@+0, v@+256 ----------------
__global__ __launch_bounds__(256) void dec_attn_k(
    const float* __restrict__ q, const float* __restrict__ kv, int ldkv,
    float* __restrict__ outp, int rpb)
{
    int hd = blockIdx.y;
    int r0 = blockIdx.x * 64;
    int b = r0 / rpb;
    __shared__ float kl[64][32];
    __shared__ float vl[64][32];
    int tid = threadIdx.x;
    for (int i = tid; i < 64 * 32; i += 256) {
        int s = i >> 5, j = i & 31;
        int64_t off = ((int64_t)(b * MPOSE + s)) * ldkv + hd * 32 + j;
        kl[s][j] = kv[off];
        vl[s][j] = kv[off + 256];
    }
    __syncthreads();
    int r  = r0 + (tid >> 2);
    int qu = (tid & 3) * 8;
    int64_t qoff = (int64_t)r * 256 + hd * 32 + qu;
    float qr[8];
#pragma unroll
    for (int j = 0; j < 8; ++j) qr[j] = q[qoff + j] * QSCALE;
    float m = -1e30f, l = 0.f;
    for (int s = 0; s < 64; ++s) {
        float d = 0.f;
#pragma unroll
        for (int j = 0; j < 8; ++j) d += qr[j] * kl[s][qu + j];
        d += __shfl_xor(d, 1);
        d += __shfl_xor(d, 2);
        float mn = fmaxf(m, d);
        l = l * __expf(m - mn) + __expf(d - mn);
        m = mn;
    }
    float acc[8] = {};
    for (int s = 0; s < 64; ++s) {
        float d = 0.f;
#pragma unroll
        for (int j = 0; j < 8; ++j) d += qr[j] * kl[s][qu + j];
        d += __shfl_xor(d, 1);
        d += __shfl_xor(d, 2);
        float wgt = __expf(d - m);
#pragma unroll
        for (int j = 0; j < 8; ++j) acc[j] += wgt * vl[s][qu + j];
    }
    float linv = 1.f / l;
#pragma unroll
    for (int j = 0; j < 8; ++j) outp[qoff + j] = acc[j] * linv;
}

// ---------------- bf16 weight arena offsets (ushort units) ----------------
static constexpr int64_t WT_QKV  = 0;
static constexpr int64_t WT_EOUT = WT_QKV  + 2*196608;
static constexpr int64_t WT_EFF1 = WT_EOUT + 2*65536;
static constexpr int64_t WT_EFF2 = WT_EFF1 + 2*262144;
static constexpr int64_t WT_DQ   = WT_EFF2 + 2*262144;
static constexpr int64_t WT_DKV  = WT_DQ   + 2*65536;
static constexpr int64_t WT_DOUT = WT_DKV  + 2*131072;
static constexpr int64_t WT_DFF1 = WT_DOUT + 2*65536;
static constexpr int64_t WT_DFF2 = WT_DFF1 + 2*262144;
static constexpr int64_t WT_SW1  = WT_DFF2 + 2*262144;
static constexpr int64_t WT_SW2  = WT_SW1 + 8192;
static constexpr int64_t WT_SW3  = WT_SW2 + 32768;
static constexpr int64_t WT_BW   = WT_SW3 + 65536;
static constexpr int64_t WT_PW   = WT_BW  + 131072;
static constexpr int64_t WT_EPE  = WT_PW  + 196608;
static constexpr int64_t WT_FC1  = WT_EPE + 131072;
static constexpr int64_t WT_FC2  = WT_FC1 + 131072;
static constexpr int64_t WT_M1   = WT_FC2 + 65536;
static constexpr int64_t WT_M2   = WT_M1  + 196608;
static constexpr int64_t WT_TOTAL = WT_M2 + 98304;

// ---------------- host orchestration ----------------
extern "C" void kernel_launch(void* const* d_in, const int* in_sizes, int n_in,
                              void* d_out, int out_size, void* d_ws, size_t ws_size,
                              hipStream_t stream)
{
    (void)in_sizes; (void)n_in; (void)out_size;
    const float* boxes     = (const float*)d_in[0];
    const float* embeds    = (const float*)d_in[1];
    const float* sizes     = (const float*)d_in[2];
    const float* pose      = (const float*)d_in[3];
    const float* line      = (const float*)d_in[4];
    const float* sw1 = (const float*)d_in[5];  const float* sb1 = (const float*)d_in[6];
    const float* sw2 = (const float*)d_in[7];  const float* sb2 = (const float*)d_in[8];
    const float* sw3 = (const float*)d_in[9];  const float* sb3 = (const float*)d_in[10];
    const float* bw  = (const float*)d_in[11]; const float* bb  = (const float*)d_in[12];
    const float* pw  = (const float*)d_in[13]; const float* pb  = (const float*)d_in[14];
    const float* lw  = (const float*)d_in[15]; const float* lb  = (const float*)d_in[16];
    const float* enc_pe_w  = (const float*)d_in[17]; const float* enc_pe_b = (const float*)d_in[18];
    const float* enc_qkv_w = (const float*)d_in[19]; const float* enc_qkv_b = (const float*)d_in[20];
    const float* enc_out_w = (const float*)d_in[21]; const float* enc_out_b = (const float*)d_in[22];
    const float* enc_ff1_w = (const float*)d_in[23]; const float* enc_ff1_b = (const float*)d_in[24];
    const float* enc_ff2_w = (const float*)d_in[25]; const float* enc_ff2_b = (const float*)d_in[26];
    const float* enc_ln1_g = (const float*)d_in[27]; const float* enc_ln1_b = (const float*)d_in[28];
    const float* enc_ln2_g = (const float*)d_in[29]; const float* enc_ln2_b = (const float*)d_in[30];
    const float* dec_q_w   = (const float*)d_in[31]; const float* dec_q_b  = (const float*)d_in[32];
    const float* dec_kv_w  = (const float*)d_in[33]; const float* dec_kv_b = (const float*)d_in[34];
    const float* dec_out_w = (const float*)d_in[35]; const float* dec_out_b = (const float*)d_in[36];
    const float* dec_ff1_w = (const float*)d_in[37]; const float* dec_ff1_b = (const float*)d_in[38];
    const float* dec_ff2_w = (const float*)d_in[39]; const float* dec_ff2_b = (const float*)d_in[40];
    const float* dec_ln1_g = (const float*)d_in[41]; const float* dec_ln1_b = (const float*)d_in[42];
    const float* dec_ln2_g = (const float*)d_in[43]; const float* dec_ln2_b = (const float*)d_in[44];
    const float* fc1_w = (const float*)d_in[45]; const float* fc1_b = (const float*)d_in[46];
    const float* fc2_w = (const float*)d_in[47]; const float* fc2_b = (const float*)d_in[48];
    const float* mln1_g = (const float*)d_in[49]; const float* mln1_b = (const float*)d_in[50];
    const float* mln2_g = (const float*)d_in[51]; const float* mln2_b = (const float*)d_in[52];
    const float* m1_w = (const float*)d_in[53]; const float* m1_b = (const float*)d_in[54];
    const float* m2_w = (const float*)d_in[55]; const float* m2_b = (const float*)d_in[56];
    float* out = (float*)d_out;

    // ---- workspace layout ----
    float* base = (float*)d_ws;
    int64_t wsf = (int64_t)(ws_size / sizeof(float));
    float* x_   = base;                       // 524288 tokens
    float* bpw_ = x_   + 524288;              // 524288 pe_tok
    float* lf   = bpw_ + 524288;              // 4096
    float* kv0  = lf   + 4096;                // 1048576 (kvAll [1024][1024]; later UV [2048][512])
    unsigned short* wt = (unsigned short*)(kv0 + 1048576);
    float* arena = (float*)(wt + WT_TOTAL);
    const int64_t LIVE_F = arena - base;
    int64_t arena_f = wsf - LIVE_F;
    if (arena_f < 0) arena_f = 0;

    // setup-phase views into arena
    float* posx  = arena;                     // 524288
    float* boxpe = posx  + 524288;            // 1048576
    float* pqkv  = boxpe + 1048576;           // 3145728 ([2048][1536])
    float* e_qkv = pqkv  + 3145728;           // 1572864
    float* e_t   = e_qkv + 1572864;           // 524288
    float* e_ff  = e_t   + 524288;            // 2097152
    float* pctx  = e_ff  + 2097152;           // 262144
    float* lm    = pctx  + 262144;            // 32768

    // pair-chunk (bf16): per-row u16 = t3 256 + zb 512 + z2 384 = 1152
    int64_t rc = ((arena_f * 2) / 1152) & ~127LL;
    if (rc > BP) rc = BP;
    if (rc < 128) rc = 128;

    // ---- stage 0: single-launch weight prep ----
    {
        WTable T;
        int nd = 0, bs = 0;
        auto add = [&](const float* src, int64_t dstOff, int K, int Nn, int Kpad) {
            T.d[nd] = { src, dstOff, K, Nn, Kpad, bs };
            bs += (Kpad / 32) * (Nn / 32);
            ++nd;
        };
        for (int i = 0; i < 2; ++i) {
            add(enc_qkv_w + (int64_t)i*196608, WT_QKV  + i*196608, 256, 768, 256);
            add(enc_out_w + (int64_t)i*65536,  WT_EOUT + i*65536,  256, 256, 256);
            add(enc_ff1_w + (int64_t)i*262144, WT_EFF1 + i*262144, 256, 1024, 256);
            add(enc_ff2_w + (int64_t)i*262144, WT_EFF2 + i*262144, 1024, 256, 1024);
            add(dec_q_w   + (int64_t)i*65536,  WT_DQ   + i*65536,  256, 256, 256);
            add(dec_kv_w  + (int64_t)i*131072, WT_DKV  + i*131072, 256, 512, 256);
            add(dec_out_w + (int64_t)i*65536,  WT_DOUT + i*65536,  256, 256, 256);
            add(dec_ff1_w + (int64_t)i*262144, WT_DFF1 + i*262144, 256, 1024, 256);
            add(dec_ff2_w + (int64_t)i*262144, WT_DFF2 + i*262144, 1024, 256, 1024);
        }
        add(sw1, WT_SW1, 36, 128, 64);
        add(sw2, WT_SW2, 128, 256, 128);
        add(sw3, WT_SW3, 256, 256, 256);
        add(bw,  WT_BW,  512, 256, 512);
        add(pw,  WT_PW,  768, 256, 768);
        add(enc_pe_w, WT_EPE, 512, 256, 512);
        add(fc1_w,             WT_FC1,         256, 256, 256);
        add(fc1_w + 256 * 256, WT_FC1 + 65536, 256, 256, 256);
        add(fc2_w, WT_FC2, 256, 256, 256);
        add(m1_w, WT_M1, 512, 384, 512);
        add(m2_w, WT_M2, 384, 256, 384);
        T.nDesc = nd;
        wprep_all_k<<<bs, 256, 0, stream>>>(T, wt);
    }

    // ---- stage A: small precomputes ----
    line_mean_k<<<8192, 256, 0, stream>>>(line, lm);
    line_proj_k<<<dim3(8, B), 256, 0, stream>>>(lm, lw, lb, lf);
    boxpe_k<<<(int)BN, 512, 0, stream>>>(boxes, sizes, boxpe);
    bgemm(stream, boxpe, nullptr, 512, wt + WT_EPE, 512, enc_pe_b, nullptr, 0, 0, nullptr,
          posx, 256, (int)BN, 256, 512, false);
    bgemm(stream, boxpe, nullptr, 512, wt + WT_BW,  512, bb, nullptr, 0, 0, lf,
          bpw_, 256, (int)BN, 256, 512, false);
    bgemm(stream, pose,  nullptr, 768, wt + WT_PW,  768, pb, nullptr, 0, 0, nullptr,
          pctx, 256, B*MPOSE, 256, 768, false);
    bgemm(stream, pctx, nullptr, 256, wt + WT_DKV, 256, dec_kv_b, nullptr, 0, 0, nullptr,
          kv0, 1024, B*MPOSE, 1024, 256, false);
    bgemm(stream, posx, nullptr, 256, wt + WT_QKV, 256, nullptr, nullptr, 0, 0, nullptr,
          pqkv, 1536, (int)BN, 1536, 256, false);

    // ---- stage B: encoder (2 layers); layer0 reads embeds directly ----
    for (int i = 0; i < 2; ++i) {
        const float* xin = (i == 0) ? embeds : x_;
        const unsigned short* Wq = wt + WT_QKV + (int64_t)i * 196608;
        bgemm(stream, xin, nullptr, 256, Wq, 256, enc_qkv_b + (int64_t)i*768,
              pqkv + i*768, 1536, 512, nullptr, e_qkv, 768, (int)BN, 768, 256, false);
        enc_attn_k<<<B * 8 * 2, 256, 0, stream>>>(e_qkv, e_t);
        tgemm16_k<<<(int)(BN / 16), 256, 0, stream>>>(e_t, 256, wt + WT_EOUT + (int64_t)i*65536, 256,
            enc_out_b + i*256, xin, enc_ln1_g + i*256, enc_ln1_b + i*256, x_, 8);
        bgemm(stream, x_, nullptr, 256, wt + WT_EFF1 + (int64_t)i*262144, 256, enc_ff1_b + i*1024,
              nullptr, 0, 0, nullptr, e_ff, 1024, (int)BN, 1024, 256, true);
        tgemm16_k<<<(int)(BN / 16), 256, 0, stream>>>(e_ff, 1024, wt + WT_EFF2 + (int64_t)i*262144, 1024,
            enc_ff2_b + i*256, x_, enc_ln2_g + i*256, enc_ln2_b + i*256, x_, 32);
    }

    // ---- stage C: decoder on tokens ----
    for (int l = 0; l < 2; ++l) {
        bgemm(stream, x_, bpw_, 256, wt + WT_DQ + (int64_t)l*65536, 256, dec_q_b + l*256,
              nullptr, 0, 0, nullptr, e_t, 256, (int)BN, 256, 256, false);
        dec_attn_k<<<dim3((int)(BN / 64), 8), 256, 0, stream>>>(e_t, kv0 + l*512, 1024, e_qkv, N);
        tgemm16_k<<<(int)(BN / 16), 256, 0, stream>>>(e_qkv, 256, wt + WT_DOUT + (int64_t)l*65536, 256,
            dec_out_b + l*256, x_, dec_ln1_g + l*256, dec_ln1_b + l*256, x_, 8);
        bgemm(stream, x_, nullptr, 256, wt + WT_DFF1 + (int64_t)l*262144, 256, dec_ff1_b + l*1024,
              nullptr, 0, 0, nullptr, e_ff, 1024, (int)BN, 1024, 256, true);
        tgemm16_k<<<(int)(BN / 16), 256, 0, stream>>>(e_ff, 1024, wt + WT_DFF2 + (int64_t)l*262144, 1024,
            dec_ff2_b + l*256, x_, dec_ln2_g + l*256, dec_ln2_b + l*256, x_, 32);
    }
    // U|V = y @ [fc1_top | fc1_bot] (bias in zprep); reuses kv0 region
    float* UV = kv0;
    bgemm(stream, x_, nullptr, 256, wt + WT_FC1, 256, nullptr, nullptr, 0, 0, nullptr,
          UV, 512, (int)BN, 512, 256, false);

    // ---- stage D: per-pair head, chunked ----
    for (int64_t c0 = 0; c0 < BP; c0 += rc) {
        int rows = (int)((BP - c0 < rc) ? (BP - c0) : rc);   // multiple of 128
        unsigned short* t3 = (unsigned short*)arena;         // rc x 256
        unsigned short* zb = t3 + (int64_t)rc * 256;         // rc x 512
        unsigned short* z2 = zb + (int64_t)rc * 512;         // rc x 384 (also sw3 temp)

        spa_k<<<rows / 128, 256, 0, stream>>>(boxes, sizes,
            wt + WT_SW1, sb1, wt + WT_SW2, sb2, t3, (int)c0);
        // t4 = relu(t3 @ sw3 + b3): N=256 in ONE col pass (NT=2, A staged once)
        hgemm_k<2,true,true><<<rows / 128, 256, 0, stream>>>(
            t3, 256, wt + WT_SW3, 256, sb3, z2, 256, 8, 1);
        // spa_out = t4 @ fc2 + b -> t3 (NT=2)
        hgemm_k<2,false,true><<<rows / 128, 256, 0, stream>>>(
            z2, 256, wt + WT_FC2, 256, fc2_b, t3, 256, 8, 1);
        zprep_k<<<rows / 4, 256, 0, stream>>>(UV, fc1_b, t3, mln1_g, mln1_b, mln2_g, mln2_b,
                                              zb, (int)c0, rows);
        // z2 = relu(zb @ m1 + b): N=384 stays 3 col-tiles (NT=1)
        hgemm_k<1,true,true><<<3 * (rows / 128), 256, 0, stream>>>(
            zb, 512, wt + WT_M1, 512, m1_b, z2, 384, 16, 3);
        // out = relu(z2 @ m2 + b): N=256 (NT=2)
        hgemm_k<2,true,false><<<rows / 128, 256, 0, stream>>>(
            z2, 384, wt + WT_M2, 384, m2_b, out + c0 * 256, 256, 12, 1);
    }
}

// Round 18
// 732.154 us; speedup vs baseline: 1.0511x; 1.0511x over previous
//
#include <hip/hip_runtime.h>
#include <stdint.h>

// ---------------- problem dims ----------------
static constexpr int B      = 16;
static constexpr int N      = 128;
static constexpr int P      = 4064;     // 32*(128-1)
static constexpr int MPOSE  = 64;
static constexpr int64_t BN = (int64_t)B * N;   // 2048
static constexpr int64_t BP = (int64_t)B * P;   // 65024 = 508*128

#define TWO_PI 6.283185307179586f
#define QSCALE 0.17677669529663687f  /* 1/sqrt(32) */

typedef __attribute__((ext_vector_type(4))) float f32x4;
typedef __attribute__((ext_vector_type(8))) short bf16x8;
typedef __attribute__((ext_vector_type(8))) unsigned short u16x8;
typedef __attribute__((ext_vector_type(4))) unsigned short u16x4;

__device__ __forceinline__ unsigned short f2bf(float f) {
    union { float f; unsigned u; } v; v.f = f;
    unsigned r = (v.u + 0x7fffu + ((v.u >> 16) & 1u)) >> 16;   // RNE
    return (unsigned short)r;
}
__device__ __forceinline__ float bf2f(unsigned short u) {
    union { unsigned u; float f; } v; v.u = (unsigned)u << 16;
    return v.f;
}
__device__ __forceinline__ void pair_xy(int p, int& x, int& y) {
    x = p / 127;
    int r = p - x * 127;
    y = (r < x) ? r : r + 1;
}
// bijective XCD-chunked swizzle (m204)
__device__ __forceinline__ int xcd_swz(int orig, int nwg) {
    int q = nwg >> 3, r = nwg & 7;
    int xcd = orig & 7, idx = orig >> 3;
    return (xcd < r ? xcd * (q + 1) : r * (q + 1) + (xcd - r) * q) + idx;
}
// async global->LDS, 16B per lane
__device__ __forceinline__ void gld16(const unsigned short* g, unsigned short* l) {
    __builtin_amdgcn_global_load_lds(
        (const __attribute__((address_space(1))) void*)g,
        (__attribute__((address_space(3))) void*)l, 16, 0, 0);
}

// ---------------- batched weight prep: W[K][N] fp32 -> Wt[N][Kpad] bf16 ----------------
struct WDesc { const float* src; int64_t dstOff; int K, Nn, Kpad, blockStart; };
struct WTable { WDesc d[29]; int nDesc; };

__global__ __launch_bounds__(256) void wprep_all_k(WTable t, unsigned short* __restrict__ wt)
{
    __shared__ float s[32][33];
    int bid = blockIdx.x;
    int di = 0;
    for (int i = 1; i < t.nDesc; ++i) if (t.d[i].blockStart <= bid) di = i;
    const WDesc& d = t.d[di];
    int lbid = bid - d.blockStart;
    int kTiles = d.Kpad >> 5;
    int k0 = (lbid % kTiles) * 32, n0 = (lbid / kTiles) * 32;
    int tx = threadIdx.x & 31, ty = threadIdx.x >> 5;
#pragma unroll
    for (int i = 0; i < 4; ++i) {
        int k = k0 + ty + i * 8;
        s[ty + i * 8][tx] = (k < d.K) ? d.src[(int64_t)k * d.Nn + n0 + tx] : 0.f;
    }
    __syncthreads();
    unsigned short* dst = wt + d.dstOff;
#pragma unroll
    for (int i = 0; i < 4; ++i) {
        int n = n0 + ty + i * 8;
        dst[(int64_t)n * d.Kpad + k0 + tx] = f2bf(s[tx][ty + i * 8]);
    }
}

// ---------------- fp32-A bf16 MFMA GEMM (token stages), 128x128 tile ----------------
template <bool RELU_OUT>
__global__ __launch_bounds__(256) void bgemm_k(
    const float* __restrict__ A, const float* __restrict__ A2, int lda,
    const unsigned short* __restrict__ Bt, int ldk,
    const float* __restrict__ bias,
    const float* __restrict__ Cadd, int addStride, int addCols,
    const float* __restrict__ lfp,
    float* __restrict__ C, int ldc,
    int kSteps)
{
    __shared__ unsigned short As[128][40];
    __shared__ unsigned short Bs[128][40];
    const int tid  = threadIdx.x;
    const int lane = tid & 63;
    const int wave = tid >> 6;
    const int wr = wave >> 1, wc = wave & 1;
    const int row0 = blockIdx.y * 128, col0 = blockIdx.x * 128;
    const int l15 = lane & 15, l4 = lane >> 4;
    const int sr = tid >> 1;
    const int sh = (tid & 1) * 16;

    f32x4 acc[4][4] = {};

    for (int ks = 0; ks < kSteps; ++ks) {
        const int k0 = ks * 32;
        {
            const int64_t off = (int64_t)(row0 + sr) * lda + k0 + sh;
            const float* ap = A + off;
            float v[16];
#pragma unroll
            for (int i = 0; i < 4; ++i) {
                float4 tv = ((const float4*)ap)[i];
                v[i*4+0] = tv.x; v[i*4+1] = tv.y; v[i*4+2] = tv.z; v[i*4+3] = tv.w;
            }
            if (A2) {
                const float* ap2 = A2 + off;
#pragma unroll
                for (int i = 0; i < 4; ++i) {
                    float4 tv = ((const float4*)ap2)[i];
                    v[i*4+0] += tv.x; v[i*4+1] += tv.y; v[i*4+2] += tv.z; v[i*4+3] += tv.w;
                }
            }
            u16x8 p0, p1;
#pragma unroll
            for (int j = 0; j < 8; ++j) { p0[j] = f2bf(v[j]); p1[j] = f2bf(v[8 + j]); }
            *(u16x8*)&As[sr][sh]     = p0;
            *(u16x8*)&As[sr][sh + 8] = p1;
        }
        {
            const unsigned short* bp = Bt + (int64_t)(col0 + sr) * ldk + k0 + sh;
            *(u16x8*)&Bs[sr][sh]     = *(const u16x8*)bp;
            *(u16x8*)&Bs[sr][sh + 8] = *(const u16x8*)(bp + 8);
        }
        __syncthreads();
        bf16x8 af[4], bfr[4];
#pragma unroll
        for (int f = 0; f < 4; ++f) {
            af[f]  = *(const bf16x8*)&As[wr * 64 + f * 16 + l15][l4 * 8];
            bfr[f] = *(const bf16x8*)&Bs[wc * 64 + f * 16 + l15][l4 * 8];
        }
#pragma unroll
        for (int i = 0; i < 4; ++i)
#pragma unroll
            for (int j = 0; j < 4; ++j)
                acc[i][j] = __builtin_amdgcn_mfma_f32_16x16x32_bf16(af[i], bfr[j], acc[i][j], 0, 0, 0);
        __syncthreads();
    }
#pragma unroll
    for (int i = 0; i < 4; ++i) {
        int rb = row0 + wr * 64 + i * 16 + l4 * 4;
#pragma unroll
        for (int j = 0; j < 4; ++j) {
            int c = col0 + wc * 64 + j * 16 + l15;
            float bv = bias ? bias[c] : 0.f;
#pragma unroll
            for (int e = 0; e < 4; ++e) {
                int r = rb + e;
                float vv = acc[i][j][e] + bv;
                if (Cadd && c < addCols) vv += Cadd[(int64_t)r * addStride + c];
                if (lfp) vv += lfp[(r >> 7) * 256 + c];
                if (RELU_OUT) vv = fmaxf(vv, 0.f);
                C[(int64_t)r * ldc + c] = vv;
            }
        }
    }
}

static void bgemm(hipStream_t st,
                  const float* A, const float* A2, int lda,
                  const unsigned short* Bt, int ldk, const float* bias,
                  const float* Cadd, int addStride, int addCols, const float* lfp,
                  float* C, int ldc, int M, int Ncols, int K, bool reluOut)
{
    dim3 g(Ncols / 128, M / 128), b(256);
    if (reluOut) bgemm_k<true><<<g,b,0,st>>>(A,A2,lda,Bt,ldk,bias,Cadd,addStride,addCols,lfp,C,ldc,K/32);
    else         bgemm_k<false><<<g,b,0,st>>>(A,A2,lda,Bt,ldk,bias,Cadd,addStride,addCols,lfp,C,ldc,K/32);
}

// ---------------- token GEMM 16x256 + residual + LayerNorm epilogue (128 blocks) ----------------
__global__ __launch_bounds__(256) void tgemm16_k(
    const float* __restrict__ A, int lda,
    const unsigned short* __restrict__ Bt, int ldk,
    const float* __restrict__ bias,
    const float* __restrict__ res,
    const float* __restrict__ g, const float* __restrict__ be,
    float* __restrict__ C, int kSteps)
{
    __shared__ unsigned short As[16][40];
    __shared__ unsigned short Bs[256][40];
    __shared__ float partS[16][4], partQ[16][4];
    __shared__ float statM[16], statI[16];
    const int tid = threadIdx.x;
    const int lane = tid & 63, w = tid >> 6;
    const int l15 = lane & 15, l4 = lane >> 4;
    const int row0 = blockIdx.x * 16;

    f32x4 acc[4] = {};
    for (int ks = 0; ks < kSteps; ++ks) {
        int k0 = ks * 32;
        if (tid < 64) {
            const float* ap = A + (int64_t)(row0 + (tid >> 2)) * lda + k0 + (tid & 3) * 8;
            float4 t0 = ((const float4*)ap)[0];
            float4 t1 = ((const float4*)ap)[1];
            u16x8 p;
            p[0]=f2bf(t0.x); p[1]=f2bf(t0.y); p[2]=f2bf(t0.z); p[3]=f2bf(t0.w);
            p[4]=f2bf(t1.x); p[5]=f2bf(t1.y); p[6]=f2bf(t1.z); p[7]=f2bf(t1.w);
            *(u16x8*)&As[tid >> 2][(tid & 3) * 8] = p;
        }
        {
            const unsigned short* bp = Bt + (int64_t)tid * ldk + k0;
#pragma unroll
            for (int q = 0; q < 4; ++q)
                *(u16x8*)&Bs[tid][q * 8] = *(const u16x8*)(bp + q * 8);
        }
        __syncthreads();
        bf16x8 af = *(const bf16x8*)&As[l15][l4 * 8];
        bf16x8 bfr[4];
#pragma unroll
        for (int f = 0; f < 4; ++f)
            bfr[f] = *(const bf16x8*)&Bs[w * 64 + f * 16 + l15][l4 * 8];
#pragma unroll
        for (int j = 0; j < 4; ++j)
            acc[j] = __builtin_amdgcn_mfma_f32_16x16x32_bf16(af, bfr[j], acc[j], 0, 0, 0);
        __syncthreads();
    }
    float ps[4] = {}, pq[4] = {};
#pragma unroll
    for (int j = 0; j < 4; ++j) {
        int c = w * 64 + j * 16 + l15;
#pragma unroll
        for (int e = 0; e < 4; ++e) {
            int r = l4 * 4 + e;
            float v = acc[j][e] + bias[c] + res[(int64_t)(row0 + r) * 256 + c];
            acc[j][e] = v;
            ps[e] += v;
            pq[e] += v * v;
        }
    }
#pragma unroll
    for (int e = 0; e < 4; ++e) {
#pragma unroll
        for (int m = 1; m < 16; m <<= 1) {
            ps[e] += __shfl_xor(ps[e], m);
            pq[e] += __shfl_xor(pq[e], m);
        }
    }
    if (l15 == 0) {
#pragma unroll
        for (int e = 0; e < 4; ++e) {
            int r = l4 * 4 + e;
            partS[r][w] = ps[e];
            partQ[r][w] = pq[e];
        }
    }
    __syncthreads();
    if (tid < 16) {
        float s = partS[tid][0] + partS[tid][1] + partS[tid][2] + partS[tid][3];
        float q = partQ[tid][0] + partQ[tid][1] + partQ[tid][2] + partQ[tid][3];
        float m = s * (1.f/256.f);
        float var = q * (1.f/256.f) - m * m;
        statM[tid] = m;
        statI[tid] = rsqrtf(var + 1e-5f);
    }
    __syncthreads();
#pragma unroll
    for (int j = 0; j < 4; ++j) {
        int c = w * 64 + j * 16 + l15;
#pragma unroll
        for (int e = 0; e < 4; ++e) {
            int r = l4 * 4 + e;
            C[(int64_t)(row0 + r) * 256 + c] = (acc[j][e] - statM[r]) * statI[r] * g[c] + be[c];
        }
    }
}

// ---------------- bf16 MFMA GEMM (pair stages): 3-deep pipeline, counted vmcnt (T4) ----------------
// Steady state: 2 tiles in flight (8 loads/wave); wait vmcnt(4) = oldest tile landed.
template <bool RELU_OUT, bool OUT_BF16>
__global__ __launch_bounds__(256) void hgemm_k(
    const unsigned short* __restrict__ A, int lda,
    const unsigned short* __restrict__ Bt, int ldk,
    const float* __restrict__ bias,
    void* __restrict__ Cv, int ldc,
    int kSteps, int nx)
{
    __shared__ unsigned short As[3][128][32];
    __shared__ unsigned short Bs[3][128][32];
    const int tid  = threadIdx.x;
    const int lane = tid & 63;
    const int wave = tid >> 6;
    const int wr = wave >> 1, wc = wave & 1;
    const int wgid = xcd_swz(blockIdx.x, gridDim.x);
    const int row0 = (wgid / nx) * 128, col0 = (wgid % nx) * 128;
    const int l15 = lane & 15, l4 = lane >> 4;
    const int srow = lane >> 2;
    const int scol = (lane & 3) * 8;

    f32x4 acc[4][4] = {};

    // prologue: stage T0 -> buf0, T1 -> buf1 (kSteps >= 2 always here)
#pragma unroll
    for (int t = 0; t < 2; ++t) {
        const int k0 = t * 32;
#pragma unroll
        for (int i = 0; i < 2; ++i) {
            int seg = wave * 2 + i;
            int r = seg * 16 + srow;
            gld16(A  + (int64_t)(row0 + r) * lda + k0 + scol, &As[t][seg * 16][0]);
            gld16(Bt + (int64_t)(col0 + r) * ldk + k0 + scol, &Bs[t][seg * 16][0]);
        }
    }

    int cur = 0;
    for (int ks = 0; ks < kSteps; ++ks) {
        // wait for oldest in-flight tile only (counted, never 0 mid-loop)
        if (ks + 1 < kSteps) asm volatile("s_waitcnt vmcnt(4)" ::: "memory");
        else                 asm volatile("s_waitcnt vmcnt(0)" ::: "memory");
        __builtin_amdgcn_s_barrier();
        asm volatile("" ::: "memory");
        // issue T(ks+2) into buf (cur+2)%3 — that buffer held T(ks-1), done by all waves
        if (ks + 2 < kSteps) {
            const int nb = (cur + 2 >= 3) ? cur - 1 : cur + 2;
            const int k0n = (ks + 2) * 32;
#pragma unroll
            for (int i = 0; i < 2; ++i) {
                int seg = wave * 2 + i;
                int r = seg * 16 + srow;
                gld16(A  + (int64_t)(row0 + r) * lda + k0n + scol, &As[nb][seg * 16][0]);
                gld16(Bt + (int64_t)(col0 + r) * ldk + k0n + scol, &Bs[nb][seg * 16][0]);
            }
        }
        // compute current tile
        bf16x8 af[4], bfr[4];
#pragma unroll
        for (int f = 0; f < 4; ++f) {
            af[f]  = *(const bf16x8*)&As[cur][wr * 64 + f * 16 + l15][l4 * 8];
            bfr[f] = *(const bf16x8*)&Bs[cur][wc * 64 + f * 16 + l15][l4 * 8];
        }
#pragma unroll
        for (int i = 0; i < 4; ++i)
#pragma unroll
            for (int j = 0; j < 4; ++j)
                acc[i][j] = __builtin_amdgcn_mfma_f32_16x16x32_bf16(af[i], bfr[j], acc[i][j], 0, 0, 0);
        __builtin_amdgcn_s_barrier();   // all waves done reading buf cur before it is re-staged
        cur = (cur + 1 >= 3) ? 0 : cur + 1;
    }
#pragma unroll
    for (int i = 0; i < 4; ++i) {
        int rb = row0 + wr * 64 + i * 16 + l4 * 4;
#pragma unroll
        for (int j = 0; j < 4; ++j) {
            int c = col0 + wc * 64 + j * 16 + l15;
            float bv = bias ? bias[c] : 0.f;
#pragma unroll
            for (int e = 0; e < 4; ++e) {
                int64_t off = (int64_t)(rb + e) * ldc + c;
                float vv = acc[i][j][e] + bv;
                if (RELU_OUT) vv = fmaxf(vv, 0.f);
                if (OUT_BF16) ((unsigned short*)Cv)[off] = f2bf(vv);
                else          ((float*)Cv)[off] = vv;
            }
        }
    }
}

// ---------------- spa_k: f36 (in-kernel) -> sw1 -> sw2 -> t3 bf16 ----------------
__global__ __launch_bounds__(256) void spa_k(
    const float* __restrict__ boxes, const float* __restrict__ sizes,
    const unsigned short* __restrict__ W1, const float* __restrict__ b1,
    const unsigned short* __restrict__ W2, const float* __restrict__ b2,
    unsigned short* __restrict__ t3out, int chunk0)
{
    __shared__ unsigned short F[128][72];
    __shared__ unsigned short Bs[128][40];
    __shared__ unsigned short D1s[128][136];
    const int tid  = threadIdx.x;
    const int lane = tid & 63;
    const int wave = tid >> 6;
    const int wr = wave >> 1, wc = wave & 1;
    const int row0 = blockIdx.x * 128;
    const int l15 = lane & 15, l4 = lane >> 4;
    const int sr = tid >> 1;
    const int sh = (tid & 1) * 16;

    if (tid < 128) {
        int gp = chunk0 + row0 + tid;
        int b = gp / P, p = gp - b * P;
        int xi, yi; pair_xy(p, xi, yi);
        const float* b1x = boxes + ((int64_t)b * N + xi) * 4;
        const float* b2x = boxes + ((int64_t)b * N + yi) * 4;
        float h = sizes[b * 2 + 0], w = sizes[b * 2 + 1];
        float c1x = (b1x[0] + b1x[2]) * 0.5f, c1y = (b1x[1] + b1x[3]) * 0.5f;
        float c2x = (b2x[0] + b2x[2]) * 0.5f, c2y = (b2x[1] + b2x[3]) * 0.5f;
        float w1 = b1x[2] - b1x[0], h1 = b1x[3] - b1x[1];
        float w2 = b2x[2] - b2x[0], h2 = b2x[3] - b2x[1];
        float a1 = w1 * h1, a2 = w2 * h2;
        float dx = fabsf(c2x - c1x) / (w1 + 1e-6f);
        float dy = fabsf(c2y - c1y) / (h1 + 1e-6f);
        float ix = fmaxf(fminf(b1x[2], b2x[2]) - fmaxf(b1x[0], b2x[0]), 0.f);
        float iy = fmaxf(fminf(b1x[3], b2x[3]) - fmaxf(b1x[1], b2x[1]), 0.f);
        float inter = ix * iy;
        float iou = inter / (a1 + a2 - inter + 1e-6f);
        float f[18];
        f[0] = c1x / w;  f[1] = c1y / h;  f[2] = c2x / w;  f[3] = c2y / h;
        f[4] = w1 / w;   f[5] = h1 / h;   f[6] = w2 / w;   f[7] = h2 / h;
        f[8] = a1 / (h * w); f[9] = a2 / (h * w); f[10] = a2 / (a1 + 1e-6f);
        f[11] = w1 / (h1 + 1e-6f); f[12] = w2 / (h2 + 1e-6f); f[13] = iou;
        f[14] = (c2x > c1x) ? dx : 0.f;  f[15] = (c2x < c1x) ? dx : 0.f;
        f[16] = (c2y > c1y) ? dy : 0.f;  f[17] = (c2y < c1y) ? dy : 0.f;
#pragma unroll
        for (int i = 0; i < 18; ++i) {
            F[tid][i]      = f2bf(f[i]);
            F[tid][18 + i] = f2bf(logf(f[i] + 1e-6f));
        }
#pragma unroll
        for (int i = 36; i < 64; ++i) F[tid][i] = 0;
    }
    __syncthreads();

    f32x4 acc1[4][4] = {};
    for (int ks = 0; ks < 2; ++ks) {
        const int k0 = ks * 32;
        {
            const unsigned short* bp = W1 + (int64_t)sr * 64 + k0 + sh;
            *(u16x8*)&Bs[sr][sh]     = *(const u16x8*)bp;
            *(u16x8*)&Bs[sr][sh + 8] = *(const u16x8*)(bp + 8);
        }
        __syncthreads();
        bf16x8 af[4], bfr[4];
#pragma unroll
        for (int f = 0; f < 4; ++f) {
            af[f]  = *(const bf16x8*)&F[wr * 64 + f * 16 + l15][k0 + l4 * 8];
            bfr[f] = *(const bf16x8*)&Bs[wc * 64 + f * 16 + l15][l4 * 8];
        }
#pragma unroll
        for (int i = 0; i < 4; ++i)
#pragma unroll
            for (int j = 0; j < 4; ++j)
                acc1[i][j] = __builtin_amdgcn_mfma_f32_16x16x32_bf16(af[i], bfr[j], acc1[i][j], 0, 0, 0);
        __syncthreads();
    }
#pragma unroll
    for (int i = 0; i < 4; ++i) {
        int rb = wr * 64 + i * 16 + l4 * 4;
#pragma unroll
        for (int j = 0; j < 4; ++j) {
            int c = wc * 64 + j * 16 + l15;
            float bv = b1[c];
#pragma unroll
            for (int e = 0; e < 4; ++e)
                D1s[rb + e][c] = f2bf(fmaxf(acc1[i][j][e] + bv, 0.f));
        }
    }
    __syncthreads();

    f32x4 acc2[2][4][4] = {};
#pragma unroll
    for (int n = 0; n < 2; ++n) {
        for (int kk = 0; kk < 4; ++kk) {
            {
                const unsigned short* bp = W2 + (int64_t)(n * 128 + sr) * 128 + kk * 32 + sh;
                *(u16x8*)&Bs[sr][sh]     = *(const u16x8*)bp;
                *(u16x8*)&Bs[sr][sh + 8] = *(const u16x8*)(bp + 8);
            }
            __syncthreads();
            bf16x8 af[4], bfr[4];
#pragma unroll
            for (int f = 0; f < 4; ++f) {
                af[f]  = *(const bf16x8*)&D1s[wr * 64 + f * 16 + l15][kk * 32 + l4 * 8];
                bfr[f] = *(const bf16x8*)&Bs[wc * 64 + f * 16 + l15][l4 * 8];
            }
#pragma unroll
            for (int i = 0; i < 4; ++i)
#pragma unroll
                for (int j = 0; j < 4; ++j)
                    acc2[n][i][j] = __builtin_amdgcn_mfma_f32_16x16x32_bf16(af[i], bfr[j], acc2[n][i][j], 0, 0, 0);
            __syncthreads();
        }
    }
#pragma unroll
    for (int n = 0; n < 2; ++n)
#pragma unroll
    for (int i = 0; i < 4; ++i) {
        int rb = row0 + wr * 64 + i * 16 + l4 * 4;
#pragma unroll
        for (int j = 0; j < 4; ++j) {
            int c = n * 128 + wc * 64 + j * 16 + l15;
            float bv = b2[c];
#pragma unroll
            for (int e = 0; e < 4; ++e)
                t3out[(int64_t)(rb + e) * 256 + c] = f2bf(fmaxf(acc2[n][i][j][e] + bv, 0.f));
        }
    }
}

// ---------------- zprep_k: zb = [relu(LN(U+V+fc1_b)) | relu(LN(t3))] bf16 ----------------
__global__ __launch_bounds__(256) void zprep_k(
    const float* __restrict__ UV, const float* __restrict__ fb,
    const unsigned short* __restrict__ t3,
    const float* __restrict__ g1, const float* __restrict__ be1,
    const float* __restrict__ g2, const float* __restrict__ be2,
    unsigned short* __restrict__ zb, int chunk0, int rows)
{
    int wave = threadIdx.x >> 6, lane = threadIdx.x & 63;
    int li = blockIdx.x * 4 + wave;
    if (li >= rows) return;
    int gp = chunk0 + li;
    int b = gp / P, p = gp - b * P;
    int xi, yi; pair_xy(p, xi, yi);
    int c = lane * 4;
    {
        float4 u  = *(const float4*)(UV + ((int64_t)(b * 128 + xi)) * 512 + c);
        float4 vv = *(const float4*)(UV + ((int64_t)(b * 128 + yi)) * 512 + 256 + c);
        float4 fbv = *(const float4*)(fb + c);
        float4 v;
        v.x = u.x + vv.x + fbv.x; v.y = u.y + vv.y + fbv.y;
        v.z = u.z + vv.z + fbv.z; v.w = u.w + vv.w + fbv.w;
        float s  = v.x + v.y + v.z + v.w;
        float sq = v.x*v.x + v.y*v.y + v.z*v.z + v.w*v.w;
#pragma unroll
        for (int off = 1; off < 64; off <<= 1) {
            s  += __shfl_xor(s, off);
            sq += __shfl_xor(sq, off);
        }
        float m = s * (1.f/256.f);
        float var = sq * (1.f/256.f) - m * m;
        float inv = rsqrtf(var + 1e-5f);
        float4 gg = *(const float4*)(g1 + c);
        float4 bb = *(const float4*)(be1 + c);
        u16x4 o;
        o[0] = f2bf(fmaxf((v.x - m) * inv * gg.x + bb.x, 0.f));
        o[1] = f2bf(fmaxf((v.y - m) * inv * gg.y + bb.y, 0.f));
        o[2] = f2bf(fmaxf((v.z - m) * inv * gg.z + bb.z, 0.f));
        o[3] = f2bf(fmaxf((v.w - m) * inv * gg.w + bb.w, 0.f));
        *(u16x4*)(zb + (int64_t)li * 512 + c) = o;
    }
    {
        u16x4 u = *(const u16x4*)(t3 + (int64_t)li * 256 + c);
        float4 v;
        v.x = bf2f(u[0]); v.y = bf2f(u[1]); v.z = bf2f(u[2]); v.w = bf2f(u[3]);
        float s  = v.x + v.y + v.z + v.w;
        float sq = v.x*v.x + v.y*v.y + v.z*v.z + v.w*v.w;
#pragma unroll
        for (int off = 1; off < 64; off <<= 1) {
            s  += __shfl_xor(s, off);
            sq += __shfl_xor(sq, off);
        }
        float m = s * (1.f/256.f);
        float var = sq * (1.f/256.f) - m * m;
        float inv = rsqrtf(var + 1e-5f);
        float4 gg = *(const float4*)(g2 + c);
        float4 bb = *(const float4*)(be2 + c);
        u16x4 o;
        o[0] = f2bf(fmaxf((v.x - m) * inv * gg.x + bb.x, 0.f));
        o[1] = f2bf(fmaxf((v.y - m) * inv * gg.y + bb.y, 0.f));
        o[2] = f2bf(fmaxf((v.z - m) * inv * gg.z + bb.z, 0.f));
        o[3] = f2bf(fmaxf((v.w - m) * inv * gg.w + bb.w, 0.f));
        *(u16x4*)(zb + (int64_t)li * 512 + 256 + c) = o;
    }
}

// ---------------- line: mean over 8x8, then proj ----------------
__global__ __launch_bounds__(256) void line_mean_k(const float* __restrict__ line, float* __restrict__ lm)
{
    int wave = threadIdx.x >> 6, lane = threadIdx.x & 63;
    int bc = blockIdx.x * 4 + wave;
    float v = line[(int64_t)bc * 64 + lane];
#pragma unroll
    for (int off = 1; off < 64; off <<= 1) v += __shfl_xor(v, off);
    if (lane == 0) lm[bc] = v * (1.f/64.f);
}

__global__ __launch_bounds__(256) void line_proj_k(
    const float* __restrict__ lm, const float* __restrict__ lw,
    const float* __restrict__ lb, float* __restrict__ lf)
{
    __shared__ float red[8][32];
    int b = blockIdx.y, jg = blockIdx.x;
    int jj = threadIdx.x & 31, cc = threadIdx.x >> 5;
    int j = jg * 32 + jj;
    const float* lmb = lm + (int64_t)b * 2048 + cc * 256;
    const float* lwp = lw + (int64_t)(cc * 256) * 256 + j;
    float acc = 0.f;
#pragma unroll 4
    for (int k = 0; k < 256; ++k) acc += lmb[k] * lwp[(int64_t)k * 256];
    red[cc][jj] = acc;
    __syncthreads();
    if (cc == 0) {
        float s = lb[j];
#pragma unroll
        for (int i = 0; i < 8; ++i) s += red[i][jj];
        lf[b * 256 + j] = s;
    }
}

// ---------------- sinusoidal box PE ----------------
__global__ __launch_bounds__(512) void boxpe_k(
    const float* __restrict__ boxes, const float* __restrict__ sizes, float* __restrict__ boxpe)
{
    int row = blockIdx.x;
    int b = row >> 7;
    int i = threadIdx.x;
    const float* bx = boxes + (int64_t)row * 4;
    float h = sizes[b * 2 + 0], w = sizes[b * 2 + 1];
    float x0 = bx[0] / w, y0 = bx[1] / h, x1 = bx[2] / w, y1 = bx[3] / h;
    int seg = i >> 7, j = i & 127, k = j >> 1;
    float val;
    switch (seg) {
        case 0: val = (y0 + y1) * 0.5f; break;
        case 1: val = (x0 + x1) * 0.5f; break;
        case 2: val = (y1 - y0); break;
        default: val = (x1 - x0); break;
    }
    float dimt = exp2f((float)k * (4.321928094887362f / 64.f));
    float arg = val * TWO_PI / dimt;
    boxpe[(int64_t)row * 512 + i] = (j & 1) ? cosf(arg) : sinf(arg);
}

// ---------------- encoder self-attn (4 lanes/query): qkv = [2048][768] ----------------
__global__ __launch_bounds__(256) void enc_attn_k(
    const float* __restrict__ qkv, float* __restrict__ outp)
{
    int bh = blockIdx.x >> 1;
    int qt = blockIdx.x & 1;
    int b = bh >> 3, hd = bh & 7;
    __shared__ float kl[128][32];
    __shared__ float vl[128][32];
    int tid = threadIdx.x;
    for (int i = tid; i < 128 * 32; i += 256) {
        int s = i >> 5, j = i & 31;
        const float* rp = qkv + ((int64_t)(b * 128 + s)) * 768 + hd * 32 + j;
        kl[s][j] = rp[256];
        vl[s][j] = rp[512];
    }
    __syncthreads();
    int q  = qt * 64 + (tid >> 2);
    int qu = (tid & 3) * 8;
    const float* qp = qkv + ((int64_t)(b * 128 + q)) * 768 + hd * 32 + qu;
    float qr[8];
#pragma unroll
    for (int j = 0; j < 8; ++j) qr[j] = qp[j] * QSCALE;
    float m = -1e30f, l = 0.f;
    for (int s = 0; s < 128; ++s) {
        float d = 0.f;
#pragma unroll
        for (int j = 0; j < 8; ++j) d += qr[j] * kl[s][qu + j];
        d += __shfl_xor(d, 1);
        d += __shfl_xor(d, 2);
        float mn = fmaxf(m, d);
        l = l * __expf(m - mn) + __expf(d - mn);
        m = mn;
    }
    float acc[8] = {};
    for (int s = 0; s < 128; ++s) {
        float d = 0.f;
#pragma unroll
        for (int j = 0; j < 8; ++j) d += qr[j] * kl[s][qu + j];
        d += __shfl_xor(d, 1);
        d += __shfl_xor(d, 2);
        float wgt = __expf(d - m);
#pragma unroll
        for (int j = 0; j < 8; ++j) acc[j] += wgt * vl[s][qu + j];
    }
    float linv = 1.f / l;
    float* op = outp + ((int64_t)(b * 128 + q)) * 256 + hd * 32 + qu;
#pragma unroll
    for (int j = 0; j < 8; ++j) op[j] = acc[j] * linv;
}

// ---------------- decoder cross-attn (4 lanes/query): kv stride ldkv, k@+0, v@+256 ----------------
__global__ __launch_bounds__(256) void dec_attn_k(
    const float* __restrict__ q, const float* __restrict__ kv, int ldkv,
    float* __restrict__ outp, int rpb)
{
    int hd = blockIdx.y;
    int r0 = blockIdx.x * 64;
    int b = r0 / rpb;
    __shared__ float kl[64][32];
    __shared__ float vl[64][32];
    int tid = threadIdx.x;
    for (int i = tid; i < 64 * 32; i += 256) {
        int s = i >> 5, j = i & 31;
        int64_t off = ((int64_t)(b * MPOSE + s)) * ldkv + hd * 32 + j;
        kl[s][j] = kv[off];
        vl[s][j] = kv[off + 256];
    }
    __syncthreads();
    int r  = r0 + (tid >> 2);
    int qu = (tid & 3) * 8;
    int64_t qoff = (int64_t)r * 256 + hd * 32 + qu;
    float qr[8];
#pragma unroll
    for (int j = 0; j < 8; ++j) qr[j] = q[qoff + j] * QSCALE;
    float m = -1e30f, l = 0.f;
    for (int s = 0; s < 64; ++s) {
        float d = 0.f;
#pragma unroll
        for (int j = 0; j < 8; ++j) d += qr[j] * kl[s][qu + j];
        d += __shfl_xor(d, 1);
        d += __shfl_xor(d, 2);
        float mn = fmaxf(m, d);
        l = l * __expf(m - mn) + __expf(d - mn);
        m = mn;
    }
    float acc[8] = {};
    for (int s = 0; s < 64; ++s) {
        float d = 0.f;
#pragma unroll
        for (int j = 0; j < 8; ++j) d += qr[j] * kl[s][qu + j];
        d += __shfl_xor(d, 1);
        d += __shfl_xor(d, 2);
        float wgt = __expf(d - m);
#pragma unroll
        for (int j = 0; j < 8; ++j) acc[j] += wgt * vl[s][qu + j];
    }
    float linv = 1.f / l;
#pragma unroll
    for (int j = 0; j < 8; ++j) outp[qoff + j] = acc[j] * linv;
}

// ---------------- bf16 weight arena offsets (ushort units) ----------------
static constexpr int64_t WT_QKV  = 0;
static constexpr int64_t WT_EOUT = WT_QKV  + 2*196608;
static constexpr int64_t WT_EFF1 = WT_EOUT + 2*65536;
static constexpr int64_t WT_EFF2 = WT_EFF1 + 2*262144;
static constexpr int64_t WT_DQ   = WT_EFF2 + 2*262144;
static constexpr int64_t WT_DKV  = WT_DQ   + 2*65536;
static constexpr int64_t WT_DOUT = WT_DKV  + 2*131072;
static constexpr int64_t WT_DFF1 = WT_DOUT + 2*65536;
static constexpr int64_t WT_DFF2 = WT_DFF1 + 2*262144;
static constexpr int64_t WT_SW1  = WT_DFF2 + 2*262144;
static constexpr int64_t WT_SW2  = WT_SW1 + 8192;
static constexpr int64_t WT_SW3  = WT_SW2 + 32768;
static constexpr int64_t WT_BW   = WT_SW3 + 65536;
static constexpr int64_t WT_PW   = WT_BW  + 131072;
static constexpr int64_t WT_EPE  = WT_PW  + 196608;
static constexpr int64_t WT_FC1  = WT_EPE + 131072;
static constexpr int64_t WT_FC2  = WT_FC1 + 131072;
static constexpr int64_t WT_M1   = WT_FC2 + 65536;
static constexpr int64_t WT_M2   = WT_M1  + 196608;
static constexpr int64_t WT_TOTAL = WT_M2 + 98304;

// ---------------- host orchestration ----------------
extern "C" void kernel_launch(void* const* d_in, const int* in_sizes, int n_in,
                              void* d_out, int out_size, void* d_ws, size_t ws_size,
                              hipStream_t stream)
{
    (void)in_sizes; (void)n_in; (void)out_size;
    const float* boxes     = (const float*)d_in[0];
    const float* embeds    = (const float*)d_in[1];
    const float* sizes     = (const float*)d_in[2];
    const float* pose      = (const float*)d_in[3];
    const float* line      = (const float*)d_in[4];
    const float* sw1 = (const float*)d_in[5];  const float* sb1 = (const float*)d_in[6];
    const float* sw2 = (const float*)d_in[7];  const float* sb2 = (const float*)d_in[8];
    const float* sw3 = (const float*)d_in[9];  const float* sb3 = (const float*)d_in[10];
    const float* bw  = (const float*)d_in[11]; const float* bb  = (const float*)d_in[12];
    const float* pw  = (const float*)d_in[13]; const float* pb  = (const float*)d_in[14];
    const float* lw  = (const float*)d_in[15]; const float* lb  = (const float*)d_in[16];
    const float* enc_pe_w  = (const float*)d_in[17]; const float* enc_pe_b = (const float*)d_in[18];
    const float* enc_qkv_w = (const float*)d_in[19]; const float* enc_qkv_b = (const float*)d_in[20];
    const float* enc_out_w = (const float*)d_in[21]; const float* enc_out_b = (const float*)d_in[22];
    const float* enc_ff1_w = (const float*)d_in[23]; const float* enc_ff1_b = (const float*)d_in[24];
    const float* enc_ff2_w = (const float*)d_in[25]; const float* enc_ff2_b = (const float*)d_in[26];
    const float* enc_ln1_g = (const float*)d_in[27]; const float* enc_ln1_b = (const float*)d_in[28];
    const float* enc_ln2_g = (const float*)d_in[29]; const float* enc_ln2_b = (const float*)d_in[30];
    const float* dec_q_w   = (const float*)d_in[31]; const float* dec_q_b  = (const float*)d_in[32];
    const float* dec_kv_w  = (const float*)d_in[33]; const float* dec_kv_b = (const float*)d_in[34];
    const float* dec_out_w = (const float*)d_in[35]; const float* dec_out_b = (const float*)d_in[36];
    const float* dec_ff1_w = (const float*)d_in[37]; const float* dec_ff1_b = (const float*)d_in[38];
    const float* dec_ff2_w = (const float*)d_in[39]; const float* dec_ff2_b = (const float*)d_in[40];
    const float* dec_ln1_g = (const float*)d_in[41]; const float* dec_ln1_b = (const float*)d_in[42];
    const float* dec_ln2_g = (const float*)d_in[43]; const float* dec_ln2_b = (const float*)d_in[44];
    const float* fc1_w = (const float*)d_in[45]; const float* fc1_b = (const float*)d_in[46];
    const float* fc2_w = (const float*)d_in[47]; const float* fc2_b = (const float*)d_in[48];
    const float* mln1_g = (const float*)d_in[49]; const float* mln1_b = (const float*)d_in[50];
    const float* mln2_g = (const float*)d_in[51]; const float* mln2_b = (const float*)d_in[52];
    const float* m1_w = (const float*)d_in[53]; const float* m1_b = (const float*)d_in[54];
    const float* m2_w = (const float*)d_in[55]; const float* m2_b = (const float*)d_in[56];
    float* out = (float*)d_out;

    // ---- workspace layout ----
    float* base = (float*)d_ws;
    int64_t wsf = (int64_t)(ws_size / sizeof(float));
    float* x_   = base;                       // 524288 tokens
    float* bpw_ = x_   + 524288;              // 524288 pe_tok
    float* lf   = bpw_ + 524288;              // 4096
    float* kv0  = lf   + 4096;                // 1048576 (kvAll [1024][1024]; later UV [2048][512])
    unsigned short* wt = (unsigned short*)(kv0 + 1048576);
    float* arena = (float*)(wt + WT_TOTAL);
    const int64_t LIVE_F = arena - base;
    int64_t arena_f = wsf - LIVE_F;
    if (arena_f < 0) arena_f = 0;

    // setup-phase views into arena
    float* posx  = arena;                     // 524288
    float* boxpe = posx  + 524288;            // 1048576
    float* pqkv  = boxpe + 1048576;           // 3145728 ([2048][1536])
    float* e_qkv = pqkv  + 3145728;           // 1572864
    float* e_t   = e_qkv + 1572864;           // 524288
    float* e_ff  = e_t   + 524288;            // 2097152
    float* pctx  = e_ff  + 2097152;           // 262144
    float* lm    = pctx  + 262144;            // 32768

    // pair-chunk (bf16): per-row u16 = t3 256 + zb 512 + z2 384 = 1152
    int64_t rc = ((arena_f * 2) / 1152) & ~127LL;
    if (rc > BP) rc = BP;
    if (rc < 128) rc = 128;

    // ---- stage 0: single-launch weight prep ----
    {
        WTable T;
        int nd = 0, bs = 0;
        auto add = [&](const float* src, int64_t dstOff, int K, int Nn, int Kpad) {
            T.d[nd] = { src, dstOff, K, Nn, Kpad, bs };
            bs += (Kpad / 32) * (Nn / 32);
            ++nd;
        };
        for (int i = 0; i < 2; ++i) {
            add(enc_qkv_w + (int64_t)i*196608, WT_QKV  + i*196608, 256, 768, 256);
            add(enc_out_w + (int64_t)i*65536,  WT_EOUT + i*65536,  256, 256, 256);
            add(enc_ff1_w + (int64_t)i*262144, WT_EFF1 + i*262144, 256, 1024, 256);
            add(enc_ff2_w + (int64_t)i*262144, WT_EFF2 + i*262144, 1024, 256, 1024);
            add(dec_q_w   + (int64_t)i*65536,  WT_DQ   + i*65536,  256, 256, 256);
            add(dec_kv_w  + (int64_t)i*131072, WT_DKV  + i*131072, 256, 512, 256);
            add(dec_out_w + (int64_t)i*65536,  WT_DOUT + i*65536,  256, 256, 256);
            add(dec_ff1_w + (int64_t)i*262144, WT_DFF1 + i*262144, 256, 1024, 256);
            add(dec_ff2_w + (int64_t)i*262144, WT_DFF2 + i*262144, 1024, 256, 1024);
        }
        add(sw1, WT_SW1, 36, 128, 64);
        add(sw2, WT_SW2, 128, 256, 128);
        add(sw3, WT_SW3, 256, 256, 256);
        add(bw,  WT_BW,  512, 256, 512);
        add(pw,  WT_PW,  768, 256, 768);
        add(enc_pe_w, WT_EPE, 512, 256, 512);
        add(fc1_w,             WT_FC1,         256, 256, 256);
        add(fc1_w + 256 * 256, WT_FC1 + 65536, 256, 256, 256);
        add(fc2_w, WT_FC2, 256, 256, 256);
        add(m1_w, WT_M1, 512, 384, 512);
        add(m2_w, WT_M2, 384, 256, 384);
        T.nDesc = nd;
        wprep_all_k<<<bs, 256, 0, stream>>>(T, wt);
    }

    // ---- stage A: small precomputes ----
    line_mean_k<<<8192, 256, 0, stream>>>(line, lm);
    line_proj_k<<<dim3(8, B), 256, 0, stream>>>(lm, lw, lb, lf);
    boxpe_k<<<(int)BN, 512, 0, stream>>>(boxes, sizes, boxpe);
    bgemm(stream, boxpe, nullptr, 512, wt + WT_EPE, 512, enc_pe_b, nullptr, 0, 0, nullptr,
          posx, 256, (int)BN, 256, 512, false);
    bgemm(stream, boxpe, nullptr, 512, wt + WT_BW,  512, bb, nullptr, 0, 0, lf,
          bpw_, 256, (int)BN, 256, 512, false);
    bgemm(stream, pose,  nullptr, 768, wt + WT_PW,  768, pb, nullptr, 0, 0, nullptr,
          pctx, 256, B*MPOSE, 256, 768, false);
    bgemm(stream, pctx, nullptr, 256, wt + WT_DKV, 256, dec_kv_b, nullptr, 0, 0, nullptr,
          kv0, 1024, B*MPOSE, 1024, 256, false);
    bgemm(stream, posx, nullptr, 256, wt + WT_QKV, 256, nullptr, nullptr, 0, 0, nullptr,
          pqkv, 1536, (int)BN, 1536, 256, false);

    // ---- stage B: encoder (2 layers); layer0 reads embeds directly ----
    for (int i = 0; i < 2; ++i) {
        const float* xin = (i == 0) ? embeds : x_;
        const unsigned short* Wq = wt + WT_QKV + (int64_t)i * 196608;
        bgemm(stream, xin, nullptr, 256, Wq, 256, enc_qkv_b + (int64_t)i*768,
              pqkv + i*768, 1536, 512, nullptr, e_qkv, 768, (int)BN, 768, 256, false);
        enc_attn_k<<<B * 8 * 2, 256, 0, stream>>>(e_qkv, e_t);
        tgemm16_k<<<(int)(BN / 16), 256, 0, stream>>>(e_t, 256, wt + WT_EOUT + (int64_t)i*65536, 256,
            enc_out_b + i*256, xin, enc_ln1_g + i*256, enc_ln1_b + i*256, x_, 8);
        bgemm(stream, x_, nullptr, 256, wt + WT_EFF1 + (int64_t)i*262144, 256, enc_ff1_b + i*1024,
              nullptr, 0, 0, nullptr, e_ff, 1024, (int)BN, 1024, 256, true);
        tgemm16_k<<<(int)(BN / 16), 256, 0, stream>>>(e_ff, 1024, wt + WT_EFF2 + (int64_t)i*262144, 1024,
            enc_ff2_b + i*256, x_, enc_ln2_g + i*256, enc_ln2_b + i*256, x_, 32);
    }

    // ---- stage C: decoder on tokens ----
    for (int l = 0; l < 2; ++l) {
        bgemm(stream, x_, bpw_, 256, wt + WT_DQ + (int64_t)l*65536, 256, dec_q_b + l*256,
              nullptr, 0, 0, nullptr, e_t, 256, (int)BN, 256, 256, false);
        dec_attn_k<<<dim3((int)(BN / 64), 8), 256, 0, stream>>>(e_t, kv0 + l*512, 1024, e_qkv, N);
        tgemm16_k<<<(int)(BN / 16), 256, 0, stream>>>(e_qkv, 256, wt + WT_DOUT + (int64_t)l*65536, 256,
            dec_out_b + l*256, x_, dec_ln1_g + l*256, dec_ln1_b + l*256, x_, 8);
        bgemm(stream, x_, nullptr, 256, wt + WT_DFF1 + (int64_t)l*262144, 256, dec_ff1_b + l*1024,
              nullptr, 0, 0, nullptr, e_ff, 1024, (int)BN, 1024, 256, true);
        tgemm16_k<<<(int)(BN / 16), 256, 0, stream>>>(e_ff, 1024, wt + WT_DFF2 + (int64_t)l*262144, 1024,
            dec_ff2_b + l*256, x_, dec_ln2_g + l*256, dec_ln2_b + l*256, x_, 32);
    }
    // U|V = y @ [fc1_top | fc1_bot] (bias in zprep); reuses kv0 region
    float* UV = kv0;
    bgemm(stream, x_, nullptr, 256, wt + WT_FC1, 256, nullptr, nullptr, 0, 0, nullptr,
          UV, 512, (int)BN, 512, 256, false);

    // ---- stage D: per-pair head, chunked ----
    for (int64_t c0 = 0; c0 < BP; c0 += rc) {
        int rows = (int)((BP - c0 < rc) ? (BP - c0) : rc);   // multiple of 128
        unsigned short* t3 = (unsigned short*)arena;         // rc x 256
        unsigned short* zb = t3 + (int64_t)rc * 256;         // rc x 512
        unsigned short* z2 = zb + (int64_t)rc * 512;         // rc x 384 (also sw3 temp)

        spa_k<<<rows / 128, 256, 0, stream>>>(boxes, sizes,
            wt + WT_SW1, sb1, wt + WT_SW2, sb2, t3, (int)c0);
        hgemm_k<true,true><<<2 * (rows / 128), 256, 0, stream>>>(
            t3, 256, wt + WT_SW3, 256, sb3, z2, 256, 8, 2);
        hgemm_k<false,true><<<2 * (rows / 128), 256, 0, stream>>>(
            z2, 256, wt + WT_FC2, 256, fc2_b, t3, 256, 8, 2);
        zprep_k<<<rows / 4, 256, 0, stream>>>(UV, fc1_b, t3, mln1_g, mln1_b, mln2_g, mln2_b,
                                              zb, (int)c0, rows);
        hgemm_k<true,true><<<3 * (rows / 128), 256, 0, stream>>>(
            zb, 512, wt + WT_M1, 512, m1_b, z2, 384, 16, 3);
        hgemm_k<true,false><<<2 * (rows / 128), 256, 0, stream>>>(
            z2, 384, wt + WT_M2, 384, m2_b, out + c0 * 256, 256, 12, 2);
    }
}